// Round 3
// baseline (219.983 us; speedup 1.0000x reference)
//
#include <hip/hip_runtime.h>

#define BB 4
#define CC 32
#define HH 480
#define WW 640
#define HWv (HH*WW)

// ---------------------------------------------------------------------------
// Kernel 1: 3x3 conv (32->8) + bias + affinity normalization, fused.
// 8 px/thread. All loads BRANCHLESS (clamped addresses + 0/1 masks) and the
// channel loop is explicitly 2-stage software-pipelined: channel c+1's rows
// are issued before channel c's FMAs, so HBM latency hides under compute.
// Output: K [B][9][H][W], K[0] = 1 - sum(a), K[1..8] = a_k = aff_k / sum|aff|
// ---------------------------------------------------------------------------
__global__ __launch_bounds__(128) void conv_gen(const float* __restrict__ kx,
                                                const float* __restrict__ Wf,
                                                const float* __restrict__ bf,
                                                float* __restrict__ K)
{
    int tid = blockIdx.x * 128 + threadIdx.x;
    const int XT = WW / 8;              // 80 thread-columns
    int x8 = tid % XT;
    int t2 = tid / XT;
    int y  = t2 % HH;
    int b  = t2 / HH;
    if (b >= BB) return;
    int x0 = x8 * 8;

    float acc[8][8];
#pragma unroll
    for (int o = 0; o < 8; ++o) {
        float bv = bf[o];
#pragma unroll
        for (int p = 0; p < 8; ++p) acc[o][p] = bv;
    }

    const float* kxb = kx + (size_t)b * CC * HWv + (size_t)y * WW + x0;

    // --- branchless boundary setup (per-thread constants) ---
    const bool xm = (x0 > 0);
    const bool xp = (x0 + 8 < WW);
    const float xmf = xm ? 1.f : 0.f;
    const float xpf = xp ? 1.f : 0.f;
    const int   eoffl = xm ? -1 : 0;    // always in-bounds
    const int   eoffr = xp ?  8 : 7;    // always in-bounds

    int   rowoff[3];
    float mc[3], ml[3], mr[3];
#pragma unroll
    for (int r = 0; r < 3; ++r) {
        int dy = r - 1;
        bool ok = (y + dy >= 0) && (y + dy < HH);
        rowoff[r] = ok ? dy * WW : 0;   // clamped: always in-plane
        mc[r] = ok ? 1.f : 0.f;
        ml[r] = mc[r] * xmf;
        mr[r] = mc[r] * xpf;
    }

    // --- branchless channel-row load: 2 float4 + 2 scalars, masked ---
    auto loadch = [&](int c, float row[3][10]) {
        const float* pl = kxb + (size_t)c * HWv;
#pragma unroll
        for (int r = 0; r < 3; ++r) {
            const float* rp = pl + rowoff[r];
            float4 v0 = *reinterpret_cast<const float4*>(rp);
            float4 v1 = *reinterpret_cast<const float4*>(rp + 4);
            float el = rp[eoffl];
            float er = rp[eoffr];
            row[r][0] = el  * ml[r];
            row[r][1] = v0.x * mc[r]; row[r][2] = v0.y * mc[r];
            row[r][3] = v0.z * mc[r]; row[r][4] = v0.w * mc[r];
            row[r][5] = v1.x * mc[r]; row[r][6] = v1.y * mc[r];
            row[r][7] = v1.z * mc[r]; row[r][8] = v1.w * mc[r];
            row[r][9] = er  * mr[r];
        }
    };

    auto compute = [&](int c, float row[3][10]) {
        const float* wc = Wf + c * 9;
#pragma unroll
        for (int o = 0; o < 8; ++o) {
            const float* wo = wc + o * (CC * 9);
#pragma unroll
            for (int r = 0; r < 3; ++r) {
#pragma unroll
                for (int t = 0; t < 3; ++t) {
                    float wv = wo[r * 3 + t];   // wave-uniform -> s_load
#pragma unroll
                    for (int p = 0; p < 8; ++p) acc[o][p] += wv * row[r][p + t];
                }
            }
        }
    };

    float bufA[3][10], bufB[3][10];
    loadch(0, bufA);
#pragma unroll 1
    for (int c = 0; c < CC; c += 2) {
        loadch(c + 1, bufB);                       // prefetch c+1
        compute(c, bufA);
        int c2 = (c + 2 < CC) ? c + 2 : CC - 1;    // clamped (harmless reload)
        loadch(c2, bufA);                          // prefetch c+2
        compute(c + 1, bufB);
    }

    // normalization: a = aff / sum|aff|; K0 = 1 - sum(a)
    float k0[8];
#pragma unroll
    for (int p = 0; p < 8; ++p) {
        float asum = 0.f;
#pragma unroll
        for (int o = 0; o < 8; ++o) asum += fabsf(acc[o][p]);
        float rinv = 1.0f / asum;
        float s = 0.f;
#pragma unroll
        for (int o = 0; o < 8; ++o) { acc[o][p] *= rinv; s += acc[o][p]; }
        k0[p] = 1.0f - s;
    }

    size_t base = (size_t)b * 9 * HWv + (size_t)y * WW + x0;
    *reinterpret_cast<float4*>(K + base)     = make_float4(k0[0], k0[1], k0[2], k0[3]);
    *reinterpret_cast<float4*>(K + base + 4) = make_float4(k0[4], k0[5], k0[6], k0[7]);
#pragma unroll
    for (int o = 0; o < 8; ++o) {
        size_t pb = base + (size_t)(o + 1) * HWv;
        *reinterpret_cast<float4*>(K + pb)     = make_float4(acc[o][0], acc[o][1], acc[o][2], acc[o][3]);
        *reinterpret_cast<float4*>(K + pb + 4) = make_float4(acc[o][4], acc[o][5], acc[o][6], acc[o][7]);
    }
}

// ---------------------------------------------------------------------------
// Kernel 2: one propagation iteration (unchanged).
// x_new[i,j] = sum_k K[k][i,j] * x[i - oi_k, j - oj_k]   (zero-padded)
// OFFSETS order: (0,0),(0,1),(0,-1),(1,0),(1,1),(1,-1),(-1,0),(-1,1),(-1,-1)
// ---------------------------------------------------------------------------
__device__ __forceinline__ void load_row6(const float* r, bool rowok, bool xm,
                                          bool xpl, float o[6])
{
    if (rowok) {
        float4 v = *reinterpret_cast<const float4*>(r);
        o[0] = xm ? r[-1] : 0.f;
        o[1] = v.x; o[2] = v.y; o[3] = v.z; o[4] = v.w;
        o[5] = xpl ? r[4] : 0.f;
    } else {
#pragma unroll
        for (int q = 0; q < 6; ++q) o[q] = 0.f;
    }
}

__global__ __launch_bounds__(256) void prop(const float* __restrict__ xin,
                                            const float* __restrict__ K,
                                            float* __restrict__ xout)
{
    int tid = blockIdx.x * 256 + threadIdx.x;
    const int XT = WW / 4;
    int x4 = tid % XT;
    int t2 = tid / XT;
    int y  = t2 % HH;
    int b  = t2 / HH;
    if (b >= BB) return;
    int x0 = x4 * 4;

    const bool xm  = (x0 > 0);
    const bool xpl = (x0 + 4 < WW);

    const float* xb = xin + (size_t)b * HWv + (size_t)y * WW + x0;
    float rm[6], r0[6], rp[6];
    load_row6(xb - WW, y > 0,      xm, xpl, rm);
    load_row6(xb,      true,       xm, xpl, r0);
    load_row6(xb + WW, y < HH - 1, xm, xpl, rp);

    const float* Kb = K + (size_t)b * 9 * HWv + (size_t)y * WW + x0;
    float kv[9][4];
#pragma unroll
    for (int k = 0; k < 9; ++k) {
        float4 v = *reinterpret_cast<const float4*>(Kb + (size_t)k * HWv);
        kv[k][0] = v.x; kv[k][1] = v.y; kv[k][2] = v.z; kv[k][3] = v.w;
    }

    float out[4];
#pragma unroll
    for (int p = 0; p < 4; ++p) {
        out[p] = kv[0][p] * r0[p + 1]
               + kv[1][p] * r0[p]
               + kv[2][p] * r0[p + 2]
               + kv[3][p] * rm[p + 1]
               + kv[4][p] * rm[p]
               + kv[5][p] * rm[p + 2]
               + kv[6][p] * rp[p + 1]
               + kv[7][p] * rp[p]
               + kv[8][p] * rp[p + 2];
    }

    *reinterpret_cast<float4*>(xout + (size_t)b * HWv + (size_t)y * WW + x0) =
        make_float4(out[0], out[1], out[2], out[3]);
}

// ---------------------------------------------------------------------------
extern "C" void kernel_launch(void* const* d_in, const int* in_sizes, int n_in,
                              void* d_out, int out_size, void* d_ws, size_t ws_size,
                              hipStream_t stream) {
    const float* kx   = (const float*)d_in[0];   // [4,32,480,640]
    const float* x_in = (const float*)d_in[1];   // [4,1,480,640]
    const float* Wf   = (const float*)d_in[2];   // [8,32,3,3]
    const float* bf   = (const float*)d_in[3];   // [8]
    float* out  = (float*)d_out;                 // [4,1,480,640]
    float* ws   = (float*)d_ws;

    float* Kbuf = ws;                             // 9*4*480*640 floats = 44.2 MB
    float* xbuf = ws + (size_t)9 * BB * HWv;      // 4*480*640 floats  =  4.9 MB

    // conv: 8 px/thread, block=128 -> 1200 blocks
    const int cthreads = BB * HH * (WW / 8);      // 153600
    conv_gen<<<cthreads / 128, 128, 0, stream>>>(kx, Wf, bf, Kbuf);

    // prop: 4 px/thread, block=256 -> 1200 blocks
    const int pthreads = BB * HH * (WW / 4);      // 307200
    const int pblocks  = pthreads / 256;          // 1200

    const float* src = x_in;
    for (int it = 0; it < 12; ++it) {
        float* dst = (it % 2 == 0) ? xbuf : out;  // it=11 (odd) -> d_out
        prop<<<pblocks, 256, 0, stream>>>(src, Kbuf, dst);
        src = dst;
    }
}

// Round 5
// 216.955 us; speedup vs baseline: 1.0140x; 1.0140x over previous
//
#include <hip/hip_runtime.h>

#define BB 4
#define CC 32
#define HH 480
#define WW 640
#define HWv (HH*WW)

// ---- conv tiling ----
#define TROWS 8
#define TCOLS 128
#define FROWS 10                    // TROWS + 2 halo rows
#define FCOLS 144                   // TCOLS + halo + 16B alignment padding
#define BUF_FLOATS 1536             // 6 issues * 256 floats (>= FROWS*FCOLS=1440)

// ---------------------------------------------------------------------------
// Kernel 1: 3x3 conv (32->8) + bias + affinity normalization.
// Per channel, a 10x144 f32 halo tile is staged into LDS with
// global_load_lds (width 16, per-lane clamped global source, linear LDS
// dest). Classic m97 double-buffer: stage(c+1) -> compute(c) -> syncthreads.
// Per-channel compute (~1150 cy) > HBM latency (~900 cy), so the vmcnt(0)
// drain inside __syncthreads costs ~0: loads being drained were issued a
// full compute-phase earlier. No inline-asm waits -> no counting fragility.
// Boundaries: clamped sources + 0/1 mask multiplies at consume time.
// ---------------------------------------------------------------------------
__global__ __launch_bounds__(128) void conv_gen(const float* __restrict__ kx,
                                                const float* __restrict__ Wf,
                                                const float* __restrict__ bf,
                                                float* __restrict__ K)
{
    __shared__ float lds[2 * BUF_FLOATS];   // 12 KB, double-buffered

    const int t    = threadIdx.x;      // 0..127
    const int tx   = t & 15;           // 0..15  (8-px column group)
    const int ty   = t >> 4;           // 0..7   (row in tile)
    const int wv   = t >> 6;           // wave 0/1
    const int lane = t & 63;

    int blk = blockIdx.x;
    const int xt = blk % (WW / TCOLS); blk /= (WW / TCOLS);
    const int yt = blk % (HH / TROWS);
    const int b  = blk / (HH / TROWS);
    const int y0 = yt * TROWS;
    const int x0 = xt * TCOLS;

    const float* kxb = kx + (size_t)b * CC * HWv;

    // ---- per-lane clamped source offsets for this wave's 3 staging issues ----
    int srcoff[3];
#pragma unroll
    for (int j = 0; j < 3; ++j) {
        int i  = wv * 3 + j;              // block issue index 0..5
        int f  = i * 256 + lane * 4;      // flat float index in fetch region
        int fr = f / FCOLS;
        int fc = f - fr * FCOLS;          // f % FCOLS (multiple of 4)
        int rg = y0 - 1 + fr; rg = rg < 0 ? 0 : (rg > HH - 1 ? HH - 1 : rg);
        int cg = x0 - 4 + fc; cg = cg < 0 ? 0 : (cg > WW - 4 ? WW - 4 : cg);
        srcoff[j] = rg * WW + cg;
    }

    // ---- channel-invariant boundary masks ----
    const float xmf = (x0 + 8 * tx      > 0 ) ? 1.f : 0.f;   // left halo valid
    const float xpf = (x0 + 8 * tx + 8  < WW) ? 1.f : 0.f;   // right halo valid
    float ml0[3], mc0[3], mr0[3];
#pragma unroll
    for (int r = 0; r < 3; ++r) {
        int ry = y0 + ty + r - 1;
        float ok = (ry >= 0 && ry < HH) ? 1.f : 0.f;
        mc0[r] = ok; ml0[r] = ok * xmf; mr0[r] = ok * xpf;
    }

    float acc[8][8];
#pragma unroll
    for (int o = 0; o < 8; ++o) {
        float bv = bf[o];
#pragma unroll
        for (int p = 0; p < 8; ++p) acc[o][p] = bv;
    }

    // ---- async stage: 3 global_load_lds (width 16) per wave per channel ----
    auto stage = [&](int c, int buf) {
        const float* src = kxb + (size_t)c * HWv;
#pragma unroll
        for (int j = 0; j < 3; ++j) {
            float* dst = &lds[buf * BUF_FLOATS + (wv * 3 + j) * 256];
            __builtin_amdgcn_global_load_lds(
                (const __attribute__((address_space(1))) void*)(src + srcoff[j]),
                (__attribute__((address_space(3))) void*)dst, 16, 0, 0);
        }
    };

    stage(0, 0);
    __syncthreads();                       // drain prologue stage (once)

#pragma unroll 1
    for (int c = 0; c < CC; ++c) {
        if (c + 1 < CC) stage(c + 1, (c + 1) & 1);   // prefetch next channel

        const float* bufp = &lds[(c & 1) * BUF_FLOATS];
        float row[3][10];
#pragma unroll
        for (int r = 0; r < 3; ++r) {
            // window = fetched cols 8tx+3 .. 8tx+12 (global x-1 .. x+8)
            const float* rp = bufp + (ty + r) * FCOLS + 8 * tx + 3;
            float4 va = *reinterpret_cast<const float4*>(rp + 1);  // 16B-aligned
            float4 vb = *reinterpret_cast<const float4*>(rp + 5);
            row[r][0] = rp[0] * ml0[r];
            row[r][1] = va.x * mc0[r]; row[r][2] = va.y * mc0[r];
            row[r][3] = va.z * mc0[r]; row[r][4] = va.w * mc0[r];
            row[r][5] = vb.x * mc0[r]; row[r][6] = vb.y * mc0[r];
            row[r][7] = vb.z * mc0[r]; row[r][8] = vb.w * mc0[r];
            row[r][9] = rp[9] * mr0[r];
        }

        const float* wc = Wf + c * 9;
#pragma unroll
        for (int o = 0; o < 8; ++o) {
#pragma unroll
            for (int r = 0; r < 3; ++r) {
#pragma unroll
                for (int s = 0; s < 3; ++s) {
                    float wvv = wc[o * (CC * 9) + r * 3 + s];  // uniform -> s_load
#pragma unroll
                    for (int p = 0; p < 8; ++p) acc[o][p] += wvv * row[r][p + s];
                }
            }
        }

        __syncthreads();   // drains stage(c+1) (issued ~1150cy ago) + read-fence
    }

    // ---- normalization: a = aff / sum|aff|; K0 = 1 - sum(a) ----
    float k0[8];
#pragma unroll
    for (int p = 0; p < 8; ++p) {
        float asum = 0.f;
#pragma unroll
        for (int o = 0; o < 8; ++o) asum += fabsf(acc[o][p]);
        float rinv = 1.0f / asum;
        float s = 0.f;
#pragma unroll
        for (int o = 0; o < 8; ++o) { acc[o][p] *= rinv; s += acc[o][p]; }
        k0[p] = 1.0f - s;
    }

    size_t base = (size_t)b * 9 * HWv + (size_t)(y0 + ty) * WW + x0 + 8 * tx;
    *reinterpret_cast<float4*>(K + base)     = make_float4(k0[0], k0[1], k0[2], k0[3]);
    *reinterpret_cast<float4*>(K + base + 4) = make_float4(k0[4], k0[5], k0[6], k0[7]);
#pragma unroll
    for (int o = 0; o < 8; ++o) {
        size_t pb = base + (size_t)(o + 1) * HWv;
        *reinterpret_cast<float4*>(K + pb)     = make_float4(acc[o][0], acc[o][1], acc[o][2], acc[o][3]);
        *reinterpret_cast<float4*>(K + pb + 4) = make_float4(acc[o][4], acc[o][5], acc[o][6], acc[o][7]);
    }
}

// ---------------------------------------------------------------------------
// Kernel 2: one propagation iteration (unchanged).
// OFFSETS order: (0,0),(0,1),(0,-1),(1,0),(1,1),(1,-1),(-1,0),(-1,1),(-1,-1)
// ---------------------------------------------------------------------------
__device__ __forceinline__ void load_row6(const float* r, bool rowok, bool xm,
                                          bool xpl, float o[6])
{
    if (rowok) {
        float4 v = *reinterpret_cast<const float4*>(r);
        o[0] = xm ? r[-1] : 0.f;
        o[1] = v.x; o[2] = v.y; o[3] = v.z; o[4] = v.w;
        o[5] = xpl ? r[4] : 0.f;
    } else {
#pragma unroll
        for (int q = 0; q < 6; ++q) o[q] = 0.f;
    }
}

__global__ __launch_bounds__(256) void prop(const float* __restrict__ xin,
                                            const float* __restrict__ K,
                                            float* __restrict__ xout)
{
    int tid = blockIdx.x * 256 + threadIdx.x;
    const int XT = WW / 4;
    int x4 = tid % XT;
    int t2 = tid / XT;
    int y  = t2 % HH;
    int b  = t2 / HH;
    if (b >= BB) return;
    int x0 = x4 * 4;

    const bool xm  = (x0 > 0);
    const bool xpl = (x0 + 4 < WW);

    const float* xb = xin + (size_t)b * HWv + (size_t)y * WW + x0;
    float rm[6], r0[6], rp[6];
    load_row6(xb - WW, y > 0,      xm, xpl, rm);
    load_row6(xb,      true,       xm, xpl, r0);
    load_row6(xb + WW, y < HH - 1, xm, xpl, rp);

    const float* Kb = K + (size_t)b * 9 * HWv + (size_t)y * WW + x0;
    float kv[9][4];
#pragma unroll
    for (int k = 0; k < 9; ++k) {
        float4 v = *reinterpret_cast<const float4*>(Kb + (size_t)k * HWv);
        kv[k][0] = v.x; kv[k][1] = v.y; kv[k][2] = v.z; kv[k][3] = v.w;
    }

    float out[4];
#pragma unroll
    for (int p = 0; p < 4; ++p) {
        out[p] = kv[0][p] * r0[p + 1]
               + kv[1][p] * r0[p]
               + kv[2][p] * r0[p + 2]
               + kv[3][p] * rm[p + 1]
               + kv[4][p] * rm[p]
               + kv[5][p] * rm[p + 2]
               + kv[6][p] * rp[p + 1]
               + kv[7][p] * rp[p]
               + kv[8][p] * rp[p + 2];
    }

    *reinterpret_cast<float4*>(xout + (size_t)b * HWv + (size_t)y * WW + x0) =
        make_float4(out[0], out[1], out[2], out[3]);
}

// ---------------------------------------------------------------------------
extern "C" void kernel_launch(void* const* d_in, const int* in_sizes, int n_in,
                              void* d_out, int out_size, void* d_ws, size_t ws_size,
                              hipStream_t stream) {
    const float* kx   = (const float*)d_in[0];   // [4,32,480,640]
    const float* x_in = (const float*)d_in[1];   // [4,1,480,640]
    const float* Wf   = (const float*)d_in[2];   // [8,32,3,3]
    const float* bf   = (const float*)d_in[3];   // [8]
    float* out  = (float*)d_out;                 // [4,1,480,640]
    float* ws   = (float*)d_ws;

    float* Kbuf = ws;                             // 9*4*480*640 floats = 44.2 MB
    float* xbuf = ws + (size_t)9 * BB * HWv;      // 4*480*640 floats  =  4.9 MB

    // conv: 1200 blocks x 128 threads (tile 8x128, 8 px/thread)
    const int cblocks = BB * (HH / TROWS) * (WW / TCOLS);   // 1200
    conv_gen<<<cblocks, 128, 0, stream>>>(kx, Wf, bf, Kbuf);

    // prop: 4 px/thread, block=256 -> 1200 blocks
    const int pthreads = BB * HH * (WW / 4);      // 307200
    const int pblocks  = pthreads / 256;          // 1200

    const float* src = x_in;
    for (int it = 0; it < 12; ++it) {
        float* dst = (it % 2 == 0) ? xbuf : out;  // it=11 (odd) -> d_out
        prop<<<pblocks, 256, 0, stream>>>(src, Kbuf, dst);
        src = dst;
    }
}